// Round 16
// baseline (2570.199 us; speedup 1.0000x reference)
//
#include <hip/hip_runtime.h>

typedef __attribute__((ext_vector_type(8))) short short8;
typedef __attribute__((ext_vector_type(4))) float f32x4;
typedef unsigned short u16;
typedef unsigned int u32;

// fast transcendentals: v_exp_f32-based, ~1e-6 error << bf16 quantization
static __device__ __forceinline__ float sigf(float x){ return 1.0f/(1.0f+__expf(-x)); }
static __device__ __forceinline__ float ftanh(float x){
    float e = __expf(2.0f*x);
    return 1.0f - 2.0f/(e + 1.0f);
}

static __device__ __forceinline__ u16 f2b(float f){
    u32 u = __float_as_uint(f);
    u += 0x7FFFu + ((u>>16)&1u);   // RNE
    return (u16)(u>>16);
}
static __device__ __forceinline__ float us2f(u16 s){ return __uint_as_float(((u32)s)<<16); }
static __device__ __forceinline__ float b2f_lo(u32 u){ return __uint_as_float(u<<16); }
static __device__ __forceinline__ float b2f_hi(u32 u){ return __uint_as_float(u & 0xffff0000u); }

static __device__ __forceinline__ void st_wt_u16(u16* p, u16 v) {
    asm volatile("global_store_short %0, %1, off sc1" :: "v"(p), "v"((u32)v) : "memory");
}
static __device__ __forceinline__ void st_wt_u32(u32* p, u32 v) {
    asm volatile("global_store_dword %0, %1, off sc1" :: "v"(p), "v"(v) : "memory");
}
static __device__ __forceinline__ u32 ld_cv(const u32* p){
    u32 v;
    asm volatile("global_load_dword %0, %1, off sc0 sc1\ns_waitcnt vmcnt(0)"
                 : "=v"(v) : "v"(p) : "memory");
    return v;
}

static __device__ __forceinline__ void hot_spin() {
    float x = 1.0f;
#pragma unroll
    for (int i = 0; i < 16; ++i) x = __builtin_fmaf(x, 1.0000001f, 1.0e-7f);
    asm volatile("" :: "v"(x));
}

// Designated waiter publishes a single release word; others poll only that.
static __device__ __forceinline__ void wait_publish(const u32* base, int n, u32 tgt, u32* rel) {
    if ((int)threadIdx.x < n) {
        const u32* p = base + (size_t)threadIdx.x*32;
        while (ld_cv(p) < tgt) hot_spin();
    }
    __syncthreads();
    if (threadIdx.x == 0) st_wt_u32(rel, tgt);
}
static __device__ __forceinline__ void wait_rel(const u32* rel, u32 tgt) {
    if (threadIdx.x == 0) {
        while (ld_cv(rel) < tgt) hot_spin();
    }
    __syncthreads();
}

// ---------------- utility kernels ----------------

__global__ __launch_bounds__(256) void k_zero(float* __restrict__ p, long n) {
    for (long i = (long)blockIdx.x*256 + threadIdx.x; i < n; i += (long)gridDim.x*256) p[i] = 0.0f;
}

// both encoder whh conversions + sentinel/encBX-slot0 zeroing in one launch
__global__ __launch_bounds__(256) void k_wenc2(const float* __restrict__ whhf,
                                               const float* __restrict__ whhb,
                                               u16* __restrict__ dst,
                                               float* __restrict__ sentF,
                                               float* __restrict__ encBX0) {
    if (blockIdx.x < 64) {
        sentF[blockIdx.x*256 + threadIdx.x] = 0.0f;                 // 16384 sentinel words
    } else if (blockIdx.x < 128) {
        encBX0[(blockIdx.x-64)*256 + threadIdx.x] = 0.0f;           // encBX slot 0 (16384 f = 32768 bf16)
    }
    long i = (long)blockIdx.x*256 + threadIdx.x;    // 0..2097151
    int half = (int)(i >> 20);
    int ii = (int)(i & 1048575);
    int n = ii >> 9, k = ii & 511;
    int j = n >> 2, q = n & 3;
    const float* w = half ? whhb : whhf;
    dst[i] = f2b(w[(size_t)(q*512 + j)*512 + k]);
}

__global__ __launch_bounds__(256) void k_xw(const float* __restrict__ table,
                                            const int* __restrict__ idx,
                                            const float* __restrict__ W,
                                            int wstride, int koff,
                                            const float* __restrict__ bias,
                                            u16* __restrict__ outU, int N,
                                            int jmask, int jshift) {
    __shared__ float Xs[32][300];
    int m0 = blockIdx.y * 32;
    int j0 = blockIdx.x * 64;
    for (int i = threadIdx.x; i < 32*300; i += 256) {
        int r = i/300, c = i - r*300;
        Xs[r][c] = table[(size_t)idx[m0+r]*300 + c];
    }
    __syncthreads();
    int tx = threadIdx.x & 63, ty = threadIdx.x >> 6;
    int jj = j0 + tx;
    const float* wr = W + (size_t)jj*wstride + koff;
    float acc[8] = {0,0,0,0,0,0,0,0};
    for (int k = 0; k < 300; ++k) {
        float w = wr[k];
#pragma unroll
        for (int mi = 0; mi < 8; ++mi) acc[mi] += Xs[ty*8+mi][k] * w;
    }
    float bv = bias[jj];
    int col = ((jj & jmask) << 2) | (jj >> jshift);
#pragma unroll
    for (int mi = 0; mi < 8; ++mi)
        outU[(size_t)(m0 + ty*8 + mi)*N + col] = f2b(acc[mi] + bv);
}

// ---------------- encoder (blocks 0-31, 8-block groups) + conversions (blocks 32-255) ----------------
// r16: group width 16->8 blocks (halves sync aggregation/skew). Wave owns 32 gate-rows
// (128 pinned weight VGPRs, two MFMA chains sharing the A-fragment).
__global__ __launch_bounds__(512, 1) void k_enc(
    const u16* __restrict__ Xf, const u16* __restrict__ Xb,
    const u16* __restrict__ WencB,
    u16* __restrict__ encBX, float* __restrict__ cfin,
    u32* __restrict__ sentE, u32* __restrict__ relE,
    const float* __restrict__ awi, const float* __restrict__ awo,
    const float* __restrict__ dwih, const float* __restrict__ dwhh,
    const float* __restrict__ genw,
    u16* __restrict__ awiTB, u16* __restrict__ awoB,
    u16* __restrict__ WdecB, u16* __restrict__ genw_b)
{
    __shared__ float SH[4224];   // 8 waves x 528 (16 batch x 32 gate-slots, stride 33)
    const int tid = threadIdx.x;
    const int bid = blockIdx.x;

    if (bid >= 32) {
        long wid = (long)(bid-32)*512 + tid;   // 0..114687
        {
            const float4* s4 = (const float4*)genw;
            ushort4* d4 = (ushort4*)genw_b;
            for (long i = wid; i < 8192000L; i += 114688L) {
                float4 v = s4[i]; ushort4 u;
                u.x=f2b(v.x); u.y=f2b(v.y); u.z=f2b(v.z); u.w=f2b(v.w);
                d4[i]=u;
            }
        }
        for (long i = wid; i < 8388608L; i += 114688L) {
            int n=(int)(i>>11), k=(int)(i&2047);
            int j=n>>2, q=n&3;
            float v=(k<1024)? dwih[(size_t)(q*1024+j)*1324+k]
                            : dwhh[(size_t)(q*1024+j)*1024+(k-1024)];
            WdecB[i]=f2b(v);
        }
        for (long i = wid; i < 1048576L; i += 114688L) {
            int kcol=(int)(i>>10), n=(int)(i&1023);
            awiTB[i]=f2b(awi[(size_t)n*1024+kcol]);
        }
        {
            const float4* s4=(const float4*)awo;
            ushort4* d4=(ushort4*)awoB;
            for (long i = wid; i < 524288L; i += 114688L) {
                float4 v=s4[i]; ushort4 u;
                u.x=f2b(v.x); u.y=f2b(v.y); u.z=f2b(v.z); u.w=f2b(v.w);
                d4[i]=u;
            }
        }
        return;
    }

    const int wv = tid >> 6, lane = tid & 63;
    const int lr = lane & 15, lk8 = (lane >> 4)*8;
    const int b_l = lane & 15, jjq = lane >> 4;

    const int dir = bid >> 4;              // 4 groups of 8: (dir, mt)
    const int mt  = (bid >> 3) & 1;
    const int g0  = bid & 24;              // group base block
    u32* relg = relE + (size_t)(g0 >> 3)*32;

    const int n0 = ((bid & 7)*8 + wv)*32;  // 32 gate-rows per wave
    const int m0 = mt*16;
    const u16* Xd = dir ? Xb : Xf;
    float* T = SH + wv*528;
    const int bb = m0 + b_l;
    const int jb = n0 >> 2;                // wave's first j (8 j per wave)

    short8 bw0[16], bw1[16];
    {
        const u16* B0 = WencB + (size_t)dir*1048576 + (size_t)(n0+lr)*512 + lk8;
        const u16* B1 = WencB + (size_t)dir*1048576 + (size_t)(n0+16+lr)*512 + lk8;
#pragma unroll
        for (int i = 0; i < 16; ++i) { bw0[i] = *(const short8*)(B0 + i*32);
                                       bw1[i] = *(const short8*)(B1 + i*32); }
    }

    float creg[2] = {0.f, 0.f};
    for (int t = 0; t < 64; ++t) {
        if (t > 0) {
            if (bid == g0) wait_publish(sentE + (size_t)g0*32, 8, (u32)t, relg);
            else           wait_rel(relg, (u32)t);
        }
        const int rslot = (t==0) ? 0 : (dir ? (65-t) : t);
        const u16* Ah = encBX + (size_t)rslot*32768 + (size_t)(m0+lr)*1024 + dir*512 + lk8;
        f32x4 acc0 = {0.f,0.f,0.f,0.f}, acc1 = {0.f,0.f,0.f,0.f};
#pragma unroll
        for (int i = 0; i < 16; ++i) {
            short8 av = *(const short8*)(Ah + i*32);
            acc0 = __builtin_amdgcn_mfma_f32_16x16x32_bf16(av, bw0[i], acc0, 0, 0, 0);
            acc1 = __builtin_amdgcn_mfma_f32_16x16x32_bf16(av, bw1[i], acc1, 0, 0, 0);
        }
        {
            const int rb = (lane>>4)*4;
#pragma unroll
            for (int r = 0; r < 4; ++r) {
                T[(rb+r)*33 + (lane&15)]      = acc0[r];
                T[(rb+r)*33 + 16 + (lane&15)] = acc1[r];
            }
        }
        __builtin_amdgcn_sched_barrier(0);
        const int s = dir ? (63-t) : t;
#pragma unroll
        for (int jj2 = 0; jj2 < 2; ++jj2) {
            const int j = jb + jj2*4 + jjq;
            ushort4 xr = *(const ushort4*)(Xd + (size_t)(s*32+bb)*2048 + j*4);
            float gi = T[b_l*33 + jj2*16 + jjq*4 + 0] + us2f(xr.x);
            float gf = T[b_l*33 + jj2*16 + jjq*4 + 1] + us2f(xr.y);
            float gg = T[b_l*33 + jj2*16 + jjq*4 + 2] + us2f(xr.z);
            float go = T[b_l*33 + jj2*16 + jjq*4 + 3] + us2f(xr.w);
            float c2 = sigf(gf)*creg[jj2] + sigf(gi)*ftanh(gg);
            float h2 = sigf(go)*ftanh(c2);
            creg[jj2] = c2;
            st_wt_u16(encBX + (size_t)(s+1)*32768 + (size_t)bb*1024 + dir*512 + j, f2b(h2));
        }
        __syncthreads();
        if (tid == 0) st_wt_u32(sentE + (size_t)bid*32, (u32)(t+1));
    }
#pragma unroll
    for (int jj2 = 0; jj2 < 2; ++jj2)
        cfin[dir*16384 + bb*512 + (jb + jj2*4 + jjq)] = creg[jj2];
}

// ---------------- encP + EOA GEMMs (+ pack folded into first 128 blocks) ----------------
__global__ __launch_bounds__(256) void k_mid(const u16* __restrict__ encBX,
                                             const u16* __restrict__ awiTB,
                                             const u16* __restrict__ awoB,
                                             u16* __restrict__ encPB,
                                             u16* __restrict__ EOAb,
                                             u16* __restrict__ Hd) {
    if (blockIdx.x < 128) {
        int gt = blockIdx.x*256 + threadIdx.x;     // 0..32767
        int b = gt >> 10, jj2 = gt & 1023;
        int d = jj2 & 1, k = jj2 >> 1;
        Hd[(size_t)b*1024 + jj2] = encBX[(size_t)(d ? 1 : 64)*32768 + (size_t)b*1024 + d*512 + k];
        Hd[(size_t)64*32768 + gt] = 0;
    }
    const int wv = threadIdx.x >> 6, lane = threadIdx.x & 63;
    const int lr = lane & 15, lk8 = (lane >> 4)*8;
    const u16* Abase = encBX + 32768;
#pragma unroll
    for (int ii = 0; ii < 4; ++ii) {
        int id = (blockIdx.x*4 + wv)*4 + ii;
        int eoa = id >> 13;           // 0: encP, 1: EOA
        int id2 = id & 8191;
        int mt2 = id2 >> 6, nt2 = id2 & 63;
        int m0 = mt2*16, n0 = nt2*16;
        const u16* Ar = Abase + (size_t)(m0+lr)*1024 + lk8;
        const u16* Br = eoa ? (awoB + (size_t)(n0+lr)*2048 + lk8)
                            : (awiTB + (size_t)(n0+lr)*1024 + lk8);
        f32x4 acc = {0.f,0.f,0.f,0.f};
#pragma unroll 8
        for (int i = 0; i < 32; ++i) {
            short8 av = *(const short8*)(Ar + i*32);
            short8 bv = *(const short8*)(Br + i*32);
            acc = __builtin_amdgcn_mfma_f32_16x16x32_bf16(av, bv, acc, 0, 0, 0);
        }
        int col = n0 + (lane&15);
        int rb = m0 + (lane>>4)*4;
#pragma unroll
        for (int r = 0; r < 4; ++r) {
            int row = rb + r;
            if (eoa) {
                int b = row & 31, s = row >> 5;
                EOAb[((size_t)b*64 + s)*1024 + col] = f2b(acc[r]);
            } else {
                encPB[(size_t)row*1024 + col] = f2b(acc[r]);
            }
        }
    }
}

// ---------------- decoder (blocks 0-127) + generator engine (blocks 128-255) ----------------
__global__ __launch_bounds__(512, 1) void k_dec(
    const u16* __restrict__ Xe,
    const u16* __restrict__ awoB, const u16* __restrict__ WdecB,
    const u16* __restrict__ encPB, const u16* __restrict__ EOAb,
    u16* __restrict__ Hd, u16* __restrict__ PEOb, u16* __restrict__ hAb,
    const float* __restrict__ cfin,
    const u16* __restrict__ genw_b, const float* __restrict__ genb, float* __restrict__ out,
    u32* __restrict__ sentA, u32* __restrict__ sentH,
    u32* __restrict__ relA, u32* __restrict__ relH)
{
    __shared__ float SH[5184];         // 4096 partials + 4x272 transpose
    __shared__ u32 CT[16512];          // c_t bf16-pairs [32 rows][516 u32] (padded)
    const int tid = threadIdx.x;
    const int bid = blockIdx.x;
    const int wv = tid >> 6, lane = tid & 63;
    const int lr = lane & 15, lk8 = (lane >> 4)*8;
    const int b_l = lane & 15, jjq = lane >> 4;

    // ======== generator engine ========
    if (bid >= 128) {
        const int gw = (bid - 128)*8 + wv;   // 0..1023
        const u16* A = Hd + 32768;           // rows 0..2047 = slots 1..64
        for (int c = 0; c < 8; ++c) {
            u32 need = (c == 7) ? 63u : (u32)(8*c + 8);
            wait_rel(relH, need);
            int tile = gw;                    // 1000 tiles: 2 mt(128) x 500 nt(64)
            if (tile < 1000) {
                int m0 = c*256 + (tile & 1)*128;
                int n0 = (tile >> 1)*64;
                f32x4 acc[8][4] = {};
                for (int k0 = 0; k0 < 1024; k0 += 32) {
                    short8 bfr[4];
#pragma unroll
                    for (int ni = 0; ni < 4; ++ni)
                        bfr[ni] = *(const short8*)(genw_b + (size_t)(n0 + ni*16 + lr)*1024 + k0 + lk8);
#pragma unroll
                    for (int mi = 0; mi < 8; ++mi) {
                        short8 a = *(const short8*)(A + (size_t)(m0 + mi*16 + lr)*1024 + k0 + lk8);
#pragma unroll
                        for (int ni = 0; ni < 4; ++ni)
                            acc[mi][ni] = __builtin_amdgcn_mfma_f32_16x16x32_bf16(a, bfr[ni], acc[mi][ni], 0, 0, 0);
                    }
                }
                int dcol = lane & 15;
                int drow = (lane >> 4)*4;
#pragma unroll
                for (int mi = 0; mi < 8; ++mi) {
                    int mbase = m0 + mi*16 + drow;
#pragma unroll
                    for (int ni = 0; ni < 4; ++ni) {
                        int n = n0 + ni*16 + dcol;
                        float bv = genb[n];
                        f32x4 v = acc[mi][ni];
#pragma unroll
                        for (int r = 0; r < 4; ++r) {
                            int m = mbase + r;
                            if (m < 2016) out[(size_t)(m + 32)*32000 + n] = v[r] + bv;
                        }
                    }
                }
            }
        }
        return;
    }

    // ======== decoder ========
    const int ntB = wv & 1, kqB = wv >> 1;
    const int jdB = bid*8 + ntB*4 + jjq;
    float cdec0 = 0.f, cdec1 = 0.f;
    if (wv < 2) {
        cdec0 = cfin[(jdB&1)*16384 + (b_l)*512 + (jdB>>1)];
        cdec1 = cfin[(jdB&1)*16384 + (16+b_l)*512 + (jdB>>1)];
    }

    short8 wp[16];
#pragma unroll
    for (int i = 0; i < 16; ++i)
        wp[i] = *(const short8*)(WdecB + (size_t)(bid*32 + ntB*16 + lr)*2048 + kqB*512 + lk8 + i*32);

    const bool isHA = (bid >= 32 && bid < 96);
    const int nth = bid - 32;
    const int mth = wv & 1, kqh = wv >> 1;
    short8 wh[8];
    if (isHA) {
#pragma unroll
        for (int i = 0; i < 8; ++i)
            wh[i] = *(const short8*)(awoB + (size_t)(nth*16+lr)*2048 + 1024 + kqh*256 + lk8 + i*32);
    }

    for (int t = 0; t < 63; ++t) {
        // ======== Phase A ========
        if (t > 0 && bid == 97) wait_publish(sentH, 128, (u32)t, relH);
        if (bid < 96) {
            if (t > 0) wait_rel(relH, (u32)t);
            if (bid < 32) {
                const int b = bid;
                float* hsh = SH; float* red = SH + 1024; float* sc = SH + 1536;
                {
                    u32 u = ((const u32*)Hd)[(size_t)t*16384 + b*512 + tid];
                    hsh[2*tid]   = b2f_lo(u);
                    hsh[2*tid+1] = b2f_hi(u);
                }
                __syncthreads();
                {
                    int s = tid >> 3, p = tid & 7;
                    const uint4* ep = (const uint4*)(encPB + (size_t)(s*32+b)*1024 + p*128);
                    const float* hk = hsh + p*128;
                    float a0=0,a1=0,a2=0,a3=0;
#pragma unroll 4
                    for (int q8 = 0; q8 < 16; ++q8) {
                        uint4 u = ep[q8];
                        a0 += b2f_lo(u.x)*hk[q8*8+0] + b2f_hi(u.x)*hk[q8*8+1];
                        a1 += b2f_lo(u.y)*hk[q8*8+2] + b2f_hi(u.y)*hk[q8*8+3];
                        a2 += b2f_lo(u.z)*hk[q8*8+4] + b2f_hi(u.z)*hk[q8*8+5];
                        a3 += b2f_lo(u.w)*hk[q8*8+6] + b2f_hi(u.w)*hk[q8*8+7];
                    }
                    red[tid] = (a0+a1)+(a2+a3);
                }
                __syncthreads();
                if (tid < 64) {
                    float v = 0;
#pragma unroll
                    for (int pp = 0; pp < 8; ++pp) v += red[tid*8+pp];
                    float m = v;
                    for (int off = 32; off; off >>= 1) m = fmaxf(m, __shfl_xor(m, off));
                    float e = __expf(v - m);
                    float ss = e;
                    for (int off = 32; off; off >>= 1) ss += __shfl_xor(ss, off);
                    sc[tid] = e / ss;
                }
                __syncthreads();
                {
                    const u32* eo = (const u32*)EOAb + (size_t)b*32768 + tid;
                    float p0 = 0, p1 = 0;
#pragma unroll 8
                    for (int s = 0; s < 64; ++s) {
                        u32 u = eo[(size_t)s*512];
                        float w = sc[s];
                        p0 += w*b2f_lo(u); p1 += w*b2f_hi(u);
                    }
                    u32 pk = (u32)f2b(p0) | ((u32)f2b(p1) << 16);
                    st_wt_u32((u32*)PEOb + (size_t)t*16384 + b*512 + tid, pk);
                }
            } else {
                const u16* Ah = Hd + (size_t)t*32768 + (size_t)(mth*16+lr)*1024 + kqh*256 + lk8;
                short8 av[8];
#pragma unroll
                for (int i = 0; i < 8; ++i) av[i] = *(const short8*)(Ah + i*32);
                f32x4 acc = {0.f,0.f,0.f,0.f};
#pragma unroll
                for (int i = 0; i < 8; ++i)
                    acc = __builtin_amdgcn_mfma_f32_16x16x32_bf16(av[i], wh[i], acc, 0, 0, 0);
#pragma unroll
                for (int r = 0; r < 4; ++r) SH[wv*256 + lane*4 + r] = acc[r];
                __syncthreads();
                if (wv < 2) {
#pragma unroll
                    for (int r = 0; r < 4; ++r) {
                        float sum = SH[(wv+0)*256 + lane*4 + r] + SH[(wv+2)*256 + lane*4 + r]
                                  + SH[(wv+4)*256 + lane*4 + r] + SH[(wv+6)*256 + lane*4 + r];
                        int m = wv*16 + (lane>>4)*4 + r;
                        st_wt_u16(hAb + (size_t)t*32768 + (size_t)m*1024 + nth*16 + (lane&15),
                                  f2b(sum));
                    }
                }
            }
            __syncthreads();
            if (tid == 0) st_wt_u32(sentA + (size_t)bid*32, (u32)(t+1));
        }

        // ======== Phase B ========
        if (bid == 96) wait_publish(sentA, 96, (u32)(t+1), relA);
        else           wait_rel(relA, (u32)(t+1));
        {
            const u32* pe = (const u32*)PEOb + (size_t)t*16384;
            const u32* ha = (const u32*)hAb + (size_t)t*16384;
#pragma unroll
            for (int ii = 0; ii < 32; ++ii) {
                int idx = tid + ii*512;
                u32 up = pe[idx], uh = ha[idx];
                float c0 = ftanh(b2f_lo(up) + b2f_lo(uh));
                float c1 = ftanh(b2f_hi(up) + b2f_hi(uh));
                int b = idx >> 9, nu = idx & 511;
                CT[b*516 + nu] = (u32)f2b(c0) | ((u32)f2b(c1) << 16);
            }
            __syncthreads();

            f32x4 a0 = {0.f,0.f,0.f,0.f}, a1 = {0.f,0.f,0.f,0.f};
            if (kqB < 2) {
                const u32* c0p = CT + (lr)*516 + kqB*256 + (lk8 >> 1);
                const u32* c1p = CT + (16+lr)*516 + kqB*256 + (lk8 >> 1);
#pragma unroll
                for (int i = 0; i < 16; ++i) {
                    short8 v0 = *(const short8*)(c0p + i*16);
                    short8 v1 = *(const short8*)(c1p + i*16);
                    a0 = __builtin_amdgcn_mfma_f32_16x16x32_bf16(v0, wp[i], a0, 0, 0, 0);
                    a1 = __builtin_amdgcn_mfma_f32_16x16x32_bf16(v1, wp[i], a1, 0, 0, 0);
                }
            } else {
                const u16* h0p = Hd + (size_t)t*32768 + (size_t)(lr)*1024 + (kqB-2)*512 + lk8;
                const u16* h1p = Hd + (size_t)t*32768 + (size_t)(16+lr)*1024 + (kqB-2)*512 + lk8;
#pragma unroll
                for (int i = 0; i < 16; ++i) {
                    short8 v0 = *(const short8*)(h0p + i*32);
                    short8 v1 = *(const short8*)(h1p + i*32);
                    a0 = __builtin_amdgcn_mfma_f32_16x16x32_bf16(v0, wp[i], a0, 0, 0, 0);
                    a1 = __builtin_amdgcn_mfma_f32_16x16x32_bf16(v1, wp[i], a1, 0, 0, 0);
                }
            }
#pragma unroll
            for (int r = 0; r < 4; ++r) {
                SH[wv*512 + lane*4 + r] = a0[r];
                SH[wv*512 + 256 + lane*4 + r] = a1[r];
            }
            __syncthreads();
            if (wv < 2) {
                const int nt = wv;
                float* T0 = SH + 4096 + (wv*2+0)*272;
                float* T1 = SH + 4096 + (wv*2+1)*272;
#pragma unroll
                for (int r = 0; r < 4; ++r) {
                    float s0 = SH[(nt+0)*512 + lane*4 + r] + SH[(nt+2)*512 + lane*4 + r]
                             + SH[(nt+4)*512 + lane*4 + r] + SH[(nt+6)*512 + lane*4 + r];
                    float s1 = SH[(nt+0)*512 + 256 + lane*4 + r] + SH[(nt+2)*512 + 256 + lane*4 + r]
                             + SH[(nt+4)*512 + 256 + lane*4 + r] + SH[(nt+6)*512 + 256 + lane*4 + r];
                    int rr = ((lane>>4)*4 + r)*17 + (lane&15);
                    T0[rr] = s0;
                    T1[rr] = s1;
                }
                __builtin_amdgcn_sched_barrier(0);
                {
                    ushort4 xr = *(const ushort4*)(Xe + (size_t)(t*32 + b_l)*4096 + jdB*4);
                    float gi = T0[b_l*17 + jjq*4 + 0] + us2f(xr.x);
                    float gf = T0[b_l*17 + jjq*4 + 1] + us2f(xr.y);
                    float gg = T0[b_l*17 + jjq*4 + 2] + us2f(xr.z);
                    float go = T0[b_l*17 + jjq*4 + 3] + us2f(xr.w);
                    float c2 = sigf(gf)*cdec0 + sigf(gi)*ftanh(gg);
                    float h2 = sigf(go)*ftanh(c2);
                    cdec0 = c2;
                    st_wt_u16(Hd + (size_t)(t+1)*32768 + (size_t)b_l*1024 + jdB, f2b(h2));
                }
                {
                    ushort4 xr = *(const ushort4*)(Xe + (size_t)(t*32 + 16 + b_l)*4096 + jdB*4);
                    float gi = T1[b_l*17 + jjq*4 + 0] + us2f(xr.x);
                    float gf = T1[b_l*17 + jjq*4 + 1] + us2f(xr.y);
                    float gg = T1[b_l*17 + jjq*4 + 2] + us2f(xr.z);
                    float go = T1[b_l*17 + jjq*4 + 3] + us2f(xr.w);
                    float c2 = sigf(gf)*cdec1 + sigf(gi)*ftanh(gg);
                    float h2 = sigf(go)*ftanh(c2);
                    cdec1 = c2;
                    st_wt_u16(Hd + (size_t)(t+1)*32768 + (size_t)(16+b_l)*1024 + jdB, f2b(h2));
                }
            }
            __syncthreads();
            if (tid == 0) st_wt_u32(sentH + (size_t)bid*32, (u32)(t+1));
        }
    }
    // final release so the generator's last chunk (slots 57..64) can run
    if (bid == 97) wait_publish(sentH, 128, 63u, relH);
}

// ---------------- log-softmax ----------------
__global__ __launch_bounds__(256) void k_lsm(float* __restrict__ out) {
    long row = 32 + blockIdx.x;
    float* p = out + row*32000L;
    float4* p4 = (float4*)p;
    int tid = threadIdx.x;
    __shared__ float sm[4];
    __shared__ float ss[4];
    float m = -1e30f;
    for (int i = tid; i < 8000; i += 256) {
        float4 v = p4[i];
        m = fmaxf(m, fmaxf(fmaxf(v.x, v.y), fmaxf(v.z, v.w)));
    }
    for (int off = 32; off; off >>= 1) m = fmaxf(m, __shfl_xor(m, off));
    if ((tid & 63) == 0) sm[tid >> 6] = m;
    __syncthreads();
    m = fmaxf(fmaxf(sm[0], sm[1]), fmaxf(sm[2], sm[3]));
    float s = 0;
    for (int i = tid; i < 8000; i += 256) {
        float4 v = p4[i];
        s += __expf(v.x - m) + __expf(v.y - m) + __expf(v.z - m) + __expf(v.w - m);
    }
    for (int off = 32; off; off >>= 1) s += __shfl_xor(s, off);
    if ((tid & 63) == 0) ss[tid >> 6] = s;
    __syncthreads();
    s = ss[0] + ss[1] + ss[2] + ss[3];
    float lse = m + __logf(s);
    for (int i = tid; i < 8000; i += 256) {
        float4 v = p4[i];
        v.x -= lse; v.y -= lse; v.z -= lse; v.w -= lse;
        p4[i] = v;
    }
}

// ---------------- launch ----------------

extern "C" void kernel_launch(void* const* d_in, const int* in_sizes, int n_in,
                              void* d_out, int out_size, void* d_ws, size_t ws_size,
                              hipStream_t stream) {
    const float* eemb  = (const float*)d_in[0];
    const float* ewihf = (const float*)d_in[1];
    const float* ewhhf = (const float*)d_in[2];
    const float* ebf   = (const float*)d_in[3];
    const float* ewihb = (const float*)d_in[4];
    const float* ewhhb = (const float*)d_in[5];
    const float* ebb   = (const float*)d_in[6];
    const float* awi   = (const float*)d_in[7];
    const float* awo   = (const float*)d_in[8];
    const float* dwih  = (const float*)d_in[9];
    const float* dwhh  = (const float*)d_in[10];
    const float* db    = (const float*)d_in[11];
    const float* demb  = (const float*)d_in[12];
    const float* genw  = (const float*)d_in[13];
    const float* genb  = (const float*)d_in[14];
    const int* srci    = (const int*)d_in[15];
    const int* trgi    = (const int*)d_in[16];
    float* out = (float*)d_out;

    float* F = (float*)d_ws;
    u32* S       = (u32*)F;
    u32* sentE   = S;                      // 32 x 32
    u32* sentA   = S + 2048;               // 96 x 32
    u32* sentH   = S + 5120;               // 128 x 32
    u32* relE    = S + 13312;              // 4 x 32
    u32* relA    = S + 13440;              // 32
    u32* relH    = S + 13472;              // 32
    float* cfin  = F + 16384;              // 32768 floats
    u16*   U     = (u16*)(F + 49152);

    u16* Xf_    = U;                       // 2048x2048
    u16* Xb_    = U + 4194304u;            // 2048x2048
    u16* Xe_    = U + 8388608u;            // 2016x4096
    u16* WencB  = U + 16646144u;           // 2 x 2048x512
    u16* awiTB  = U + 18743296u;           // 1024x1024
    u16* awoB   = U + 19791872u;           // 1024x2048
    u16* WdecB  = U + 21889024u;           // 4096x2048
    u16* genw_b = U + 30277632u;           // 32000x1024
    u16* encBX  = U + 63045632u;           // 65 x 32x1024
    u16* Hd     = U + 65175552u;           // 65 x 32x1024
    u16* PEOb   = U + 67305472u;           // 63 x 32x1024
    u16* hAb    = U + 69369856u;           // 63 x 32x1024
    u16* encPB  = U + 71434240u;           // 2048x1024
    u16* EOAb   = U + 73531392u;           // 32 x 64 x 1024

    k_zero<<<2048, 256, 0, stream>>>(out, 1024000L);   // t=0 output rows

    k_xw<<<dim3(32, 64), 256, 0, stream>>>(eemb, srci, ewihf, 300, 0, ebf, Xf_, 2048, 511, 9);
    k_xw<<<dim3(32, 64), 256, 0, stream>>>(eemb, srci, ewihb, 300, 0, ebb, Xb_, 2048, 511, 9);
    k_xw<<<dim3(64, 63), 256, 0, stream>>>(demb, trgi, dwih, 1324, 1024, db, Xe_, 4096, 1023, 10);

    // whh conversions + sentinel zeroing + encBX slot-0 zeroing
    k_wenc2<<<8192, 256, 0, stream>>>(ewhhf, ewhhb, WencB, F, (float*)encBX);

    // encoder (blocks 0-31, 8-block groups) + remaining weight conversions (blocks 32-255)
    k_enc<<<256, 512, 0, stream>>>(Xf_, Xb_, WencB, encBX, cfin, sentE, relE,
                                   awi, awo, dwih, dwhh, genw,
                                   awiTB, awoB, WdecB, genw_b);
    // encP + EOA GEMMs + pack fold
    k_mid<<<1024, 256, 0, stream>>>(encBX, awiTB, awoB, encPB, EOAb, Hd);

    // decoder (128 blocks) + generator engine (128 blocks)
    k_dec<<<256, 512, 0, stream>>>(Xe_, awoB, WdecB, encPB, EOAb,
                                   Hd, PEOb, hAb, cfin,
                                   genw_b, genb, out,
                                   sentA, sentH, relA, relH);

    k_lsm<<<2016, 256, 0, stream>>>(out);
}

// Round 17
// 2470.872 us; speedup vs baseline: 1.0402x; 1.0402x over previous
//
#include <hip/hip_runtime.h>

typedef __attribute__((ext_vector_type(8))) short short8;
typedef __attribute__((ext_vector_type(4))) float f32x4;
typedef unsigned short u16;
typedef unsigned int u32;

// fast transcendentals: v_exp_f32-based, ~1e-6 error << bf16 quantization
static __device__ __forceinline__ float sigf(float x){ return 1.0f/(1.0f+__expf(-x)); }
static __device__ __forceinline__ float ftanh(float x){
    float e = __expf(2.0f*x);
    return 1.0f - 2.0f/(e + 1.0f);
}

static __device__ __forceinline__ u16 f2b(float f){
    u32 u = __float_as_uint(f);
    u += 0x7FFFu + ((u>>16)&1u);   // RNE
    return (u16)(u>>16);
}
static __device__ __forceinline__ float us2f(u16 s){ return __uint_as_float(((u32)s)<<16); }
static __device__ __forceinline__ float b2f_lo(u32 u){ return __uint_as_float(u<<16); }
static __device__ __forceinline__ float b2f_hi(u32 u){ return __uint_as_float(u & 0xffff0000u); }

static __device__ __forceinline__ void st_wt_u16(u16* p, u16 v) {
    asm volatile("global_store_short %0, %1, off sc1" :: "v"(p), "v"((u32)v) : "memory");
}
static __device__ __forceinline__ void st_wt_u32(u32* p, u32 v) {
    asm volatile("global_store_dword %0, %1, off sc1" :: "v"(p), "v"(v) : "memory");
}
static __device__ __forceinline__ u32 ld_cv(const u32* p){
    u32 v;
    asm volatile("global_load_dword %0, %1, off sc0 sc1\ns_waitcnt vmcnt(0)"
                 : "=v"(v) : "v"(p) : "memory");
    return v;
}

static __device__ __forceinline__ void hot_spin() {
    float x = 1.0f;
#pragma unroll
    for (int i = 0; i < 16; ++i) x = __builtin_fmaf(x, 1.0000001f, 1.0e-7f);
    asm volatile("" :: "v"(x));
}

// Designated waiter publishes a single release word; others poll only that.
static __device__ __forceinline__ void wait_publish(const u32* base, int n, u32 tgt, u32* rel) {
    if ((int)threadIdx.x < n) {
        const u32* p = base + (size_t)threadIdx.x*32;
        while (ld_cv(p) < tgt) hot_spin();
    }
    __syncthreads();
    if (threadIdx.x == 0) st_wt_u32(rel, tgt);
}
static __device__ __forceinline__ void wait_rel(const u32* rel, u32 tgt) {
    if (threadIdx.x == 0) {
        while (ld_cv(rel) < tgt) hot_spin();
    }
    __syncthreads();
}

// ---------------- utility kernels ----------------

__global__ __launch_bounds__(256) void k_zero(float* __restrict__ p, long n) {
    for (long i = (long)blockIdx.x*256 + threadIdx.x; i < n; i += (long)gridDim.x*256) p[i] = 0.0f;
}

// whh conversions + sentinel zeroing + encBX slot-0 zeroing in one launch
__global__ __launch_bounds__(256) void k_wenc2(const float* __restrict__ whhf,
                                               const float* __restrict__ whhb,
                                               u16* __restrict__ dst,
                                               float* __restrict__ sentF,
                                               float* __restrict__ encBX0) {
    if (blockIdx.x < 64) {
        sentF[blockIdx.x*256 + threadIdx.x] = 0.0f;                 // 16384 sentinel words
    } else if (blockIdx.x < 128) {
        encBX0[(blockIdx.x-64)*256 + threadIdx.x] = 0.0f;           // encBX slot 0
    }
    long i = (long)blockIdx.x*256 + threadIdx.x;    // 0..2097151
    int half = (int)(i >> 20);
    int ii = (int)(i & 1048575);
    int n = ii >> 9, k = ii & 511;
    int j = n >> 2, q = n & 3;
    const float* w = half ? whhb : whhf;
    dst[i] = f2b(w[(size_t)(q*512 + j)*512 + k]);
}

__global__ __launch_bounds__(256) void k_xw(const float* __restrict__ table,
                                            const int* __restrict__ idx,
                                            const float* __restrict__ W,
                                            int wstride, int koff,
                                            const float* __restrict__ bias,
                                            u16* __restrict__ outU, int N,
                                            int jmask, int jshift) {
    __shared__ float Xs[32][300];
    int m0 = blockIdx.y * 32;
    int j0 = blockIdx.x * 64;
    for (int i = threadIdx.x; i < 32*300; i += 256) {
        int r = i/300, c = i - r*300;
        Xs[r][c] = table[(size_t)idx[m0+r]*300 + c];
    }
    __syncthreads();
    int tx = threadIdx.x & 63, ty = threadIdx.x >> 6;
    int jj = j0 + tx;
    const float* wr = W + (size_t)jj*wstride + koff;
    float acc[8] = {0,0,0,0,0,0,0,0};
    for (int k = 0; k < 300; ++k) {
        float w = wr[k];
#pragma unroll
        for (int mi = 0; mi < 8; ++mi) acc[mi] += Xs[ty*8+mi][k] * w;
    }
    float bv = bias[jj];
    int col = ((jj & jmask) << 2) | (jj >> jshift);
#pragma unroll
    for (int mi = 0; mi < 8; ++mi)
        outU[(size_t)(m0 + ty*8 + mi)*N + col] = f2b(acc[mi] + bv);
}

// ---------------- encoder (blocks 0-63, 16-block groups) + conversions (blocks 64-255) ----------------
__global__ __launch_bounds__(512, 1) void k_enc(
    const u16* __restrict__ Xf, const u16* __restrict__ Xb,
    const u16* __restrict__ WencB,
    u16* __restrict__ encBX, float* __restrict__ cfin,
    u32* __restrict__ sentE, u32* __restrict__ relE,
    const float* __restrict__ awi, const float* __restrict__ awo,
    const float* __restrict__ dwih, const float* __restrict__ dwhh,
    const float* __restrict__ genw,
    u16* __restrict__ awiTB, u16* __restrict__ awoB,
    u16* __restrict__ WdecB, u16* __restrict__ genw_b)
{
    __shared__ float SH[2304];
    const int tid = threadIdx.x;
    const int bid = blockIdx.x;

    if (bid >= 64) {
        long wid = (long)(bid-64)*512 + tid;   // 0..98303
        {
            const float4* s4 = (const float4*)genw;
            ushort4* d4 = (ushort4*)genw_b;
            for (long i = wid; i < 8192000L; i += 98304L) {
                float4 v = s4[i]; ushort4 u;
                u.x=f2b(v.x); u.y=f2b(v.y); u.z=f2b(v.z); u.w=f2b(v.w);
                d4[i]=u;
            }
        }
        for (long i = wid; i < 8388608L; i += 98304L) {
            int n=(int)(i>>11), k=(int)(i&2047);
            int j=n>>2, q=n&3;
            float v=(k<1024)? dwih[(size_t)(q*1024+j)*1324+k]
                            : dwhh[(size_t)(q*1024+j)*1024+(k-1024)];
            WdecB[i]=f2b(v);
        }
        for (long i = wid; i < 1048576L; i += 98304L) {
            int kcol=(int)(i>>10), n=(int)(i&1023);
            awiTB[i]=f2b(awi[(size_t)n*1024+kcol]);
        }
        {
            const float4* s4=(const float4*)awo;
            ushort4* d4=(ushort4*)awoB;
            for (long i = wid; i < 524288L; i += 98304L) {
                float4 v=s4[i]; ushort4 u;
                u.x=f2b(v.x); u.y=f2b(v.y); u.z=f2b(v.z); u.w=f2b(v.w);
                d4[i]=u;
            }
        }
        return;
    }

    const int wv = tid >> 6, lane = tid & 63;
    const int gwave = bid*8 + wv;
    const int lr = lane & 15, lk8 = (lane >> 4)*8;
    const int b_l = lane & 15, jjq = lane >> 4;
    const int g0 = bid & 48;
    u32* relg = relE + (size_t)(g0 >> 4)*32;

    const int dir = gwave >> 8;
    const int mt = (gwave >> 7) & 1;
    const int nt = gwave & 127;
    const int m0 = mt*16, n0 = nt*16;
    const u16* Bw = WencB + (size_t)dir*1048576 + (size_t)(n0+lr)*512 + lk8;
    const u16* Xd = dir ? Xb : Xf;
    float* T = SH + wv*272;
    const int bb = m0 + b_l;
    const int j = nt*4 + jjq;

    short8 bw[16];
#pragma unroll
    for (int i = 0; i < 16; ++i) bw[i] = *(const short8*)(Bw + i*32);

    float creg = 0.f;
    for (int t = 0; t < 64; ++t) {
        if (t > 0) {
            if (bid == g0) wait_publish(sentE + (size_t)g0*32, 16, (u32)t, relg);
            else           wait_rel(relg, (u32)t);
        }
        const int rslot = (t==0) ? 0 : (dir ? (65-t) : t);
        const u16* Ah = encBX + (size_t)rslot*32768 + (size_t)(m0+lr)*1024 + dir*512 + lk8;
        short8 av[16];
#pragma unroll
        for (int i = 0; i < 16; ++i) av[i] = *(const short8*)(Ah + i*32);
        f32x4 acc = {0.f,0.f,0.f,0.f};
#pragma unroll
        for (int i = 0; i < 16; ++i)
            acc = __builtin_amdgcn_mfma_f32_16x16x32_bf16(av[i], bw[i], acc, 0, 0, 0);
        {
            const int rb = (lane>>4)*4;
#pragma unroll
            for (int r = 0; r < 4; ++r) T[(rb+r)*17 + (lane&15)] = acc[r];
        }
        __builtin_amdgcn_sched_barrier(0);
        const int s = dir ? (63-t) : t;
        ushort4 xr = *(const ushort4*)(Xd + (size_t)(s*32+bb)*2048 + n0 + jjq*4);
        float gi = T[b_l*17 + jjq*4 + 0] + us2f(xr.x);
        float gf = T[b_l*17 + jjq*4 + 1] + us2f(xr.y);
        float gg = T[b_l*17 + jjq*4 + 2] + us2f(xr.z);
        float go = T[b_l*17 + jjq*4 + 3] + us2f(xr.w);
        float c2 = sigf(gf)*creg + sigf(gi)*ftanh(gg);
        float h2 = sigf(go)*ftanh(c2);
        creg = c2;
        st_wt_u16(encBX + (size_t)(s+1)*32768 + (size_t)bb*1024 + dir*512 + j, f2b(h2));
        __syncthreads();
        if (tid == 0) st_wt_u32(sentE + (size_t)bid*32, (u32)(t+1));
    }
    cfin[dir*16384 + bb*512 + j] = creg;
}

// ---------------- encP + EOA GEMMs (+ pack folded into first 128 blocks) ----------------
__global__ __launch_bounds__(256) void k_mid(const u16* __restrict__ encBX,
                                             const u16* __restrict__ awiTB,
                                             const u16* __restrict__ awoB,
                                             u16* __restrict__ encPB,
                                             u16* __restrict__ EOAb,
                                             u16* __restrict__ Hd) {
    if (blockIdx.x < 128) {
        int gt = blockIdx.x*256 + threadIdx.x;     // 0..32767
        int b = gt >> 10, jj2 = gt & 1023;
        int d = jj2 & 1, k = jj2 >> 1;
        Hd[(size_t)b*1024 + jj2] = encBX[(size_t)(d ? 1 : 64)*32768 + (size_t)b*1024 + d*512 + k];
        Hd[(size_t)64*32768 + gt] = 0;
    }
    const int wv = threadIdx.x >> 6, lane = threadIdx.x & 63;
    const int lr = lane & 15, lk8 = (lane >> 4)*8;
    const u16* Abase = encBX + 32768;
#pragma unroll
    for (int ii = 0; ii < 4; ++ii) {
        int id = (blockIdx.x*4 + wv)*4 + ii;
        int eoa = id >> 13;           // 0: encP, 1: EOA
        int id2 = id & 8191;
        int mt2 = id2 >> 6, nt2 = id2 & 63;
        int m0 = mt2*16, n0 = nt2*16;
        const u16* Ar = Abase + (size_t)(m0+lr)*1024 + lk8;
        const u16* Br = eoa ? (awoB + (size_t)(n0+lr)*2048 + lk8)
                            : (awiTB + (size_t)(n0+lr)*1024 + lk8);
        f32x4 acc = {0.f,0.f,0.f,0.f};
#pragma unroll 8
        for (int i = 0; i < 32; ++i) {
            short8 av = *(const short8*)(Ar + i*32);
            short8 bv = *(const short8*)(Br + i*32);
            acc = __builtin_amdgcn_mfma_f32_16x16x32_bf16(av, bv, acc, 0, 0, 0);
        }
        int col = n0 + (lane&15);
        int rb = m0 + (lane>>4)*4;
#pragma unroll
        for (int r = 0; r < 4; ++r) {
            int row = rb + r;
            if (eoa) {
                int b = row & 31, s = row >> 5;
                EOAb[((size_t)b*64 + s)*1024 + col] = f2b(acc[r]);
            } else {
                encPB[(size_t)row*1024 + col] = f2b(acc[r]);
            }
        }
    }
}

// ---------------- decoder (blocks 0-127) + generator engine (blocks 128-255) ----------------
__global__ __launch_bounds__(512, 1) void k_dec(
    const u16* __restrict__ Xe,
    const u16* __restrict__ awoB, const u16* __restrict__ WdecB,
    const u16* __restrict__ encPB, const u16* __restrict__ EOAb,
    u16* __restrict__ Hd, u16* __restrict__ PEOb, u16* __restrict__ hAb,
    const float* __restrict__ cfin,
    const u16* __restrict__ genw_b, const float* __restrict__ genb, float* __restrict__ out,
    u32* __restrict__ sentA, u32* __restrict__ sentH,
    u32* __restrict__ relA, u32* __restrict__ relH)
{
    __shared__ float SH[5184];
    __shared__ u32 CT[16512];
    const int tid = threadIdx.x;
    const int bid = blockIdx.x;
    const int wv = tid >> 6, lane = tid & 63;
    const int lr = lane & 15, lk8 = (lane >> 4)*8;
    const int b_l = lane & 15, jjq = lane >> 4;

    // ======== generator engine ========
    if (bid >= 128) {
        const int gw = (bid - 128)*8 + wv;   // 0..1023
        const u16* A = Hd + 32768;
        for (int c = 0; c < 8; ++c) {
            u32 need = (c == 7) ? 63u : (u32)(8*c + 8);
            wait_rel(relH, need);
            int tile = gw;
            if (tile < 1000) {
                int m0 = c*256 + (tile & 1)*128;
                int n0 = (tile >> 1)*64;
                f32x4 acc[8][4] = {};
                for (int k0 = 0; k0 < 1024; k0 += 32) {
                    short8 bfr[4];
#pragma unroll
                    for (int ni = 0; ni < 4; ++ni)
                        bfr[ni] = *(const short8*)(genw_b + (size_t)(n0 + ni*16 + lr)*1024 + k0 + lk8);
#pragma unroll
                    for (int mi = 0; mi < 8; ++mi) {
                        short8 a = *(const short8*)(A + (size_t)(m0 + mi*16 + lr)*1024 + k0 + lk8);
#pragma unroll
                        for (int ni = 0; ni < 4; ++ni)
                            acc[mi][ni] = __builtin_amdgcn_mfma_f32_16x16x32_bf16(a, bfr[ni], acc[mi][ni], 0, 0, 0);
                    }
                }
                int dcol = lane & 15;
                int drow = (lane >> 4)*4;
#pragma unroll
                for (int mi = 0; mi < 8; ++mi) {
                    int mbase = m0 + mi*16 + drow;
#pragma unroll
                    for (int ni = 0; ni < 4; ++ni) {
                        int n = n0 + ni*16 + dcol;
                        float bv = genb[n];
                        f32x4 v = acc[mi][ni];
#pragma unroll
                        for (int r = 0; r < 4; ++r) {
                            int m = mbase + r;
                            if (m < 2016) out[(size_t)(m + 32)*32000 + n] = v[r] + bv;
                        }
                    }
                }
            }
        }
        return;
    }

    // ======== decoder ========
    const int ntB = wv & 1, kqB = wv >> 1;
    const int jdB = bid*8 + ntB*4 + jjq;
    float cdec0 = 0.f, cdec1 = 0.f;
    if (wv < 2) {
        cdec0 = cfin[(jdB&1)*16384 + (b_l)*512 + (jdB>>1)];
        cdec1 = cfin[(jdB&1)*16384 + (16+b_l)*512 + (jdB>>1)];
    }

    short8 wp[16];
#pragma unroll
    for (int i = 0; i < 16; ++i)
        wp[i] = *(const short8*)(WdecB + (size_t)(bid*32 + ntB*16 + lr)*2048 + kqB*512 + lk8 + i*32);

    const bool isHA = (bid >= 32 && bid < 96);
    const int nth = bid - 32;
    const int mth = wv & 1, kqh = wv >> 1;
    short8 wh[8];
    if (isHA) {
#pragma unroll
        for (int i = 0; i < 8; ++i)
            wh[i] = *(const short8*)(awoB + (size_t)(nth*16+lr)*2048 + 1024 + kqh*256 + lk8 + i*32);
    }

    for (int t = 0; t < 63; ++t) {
        // ======== Phase A ========
        if (t > 0 && bid == 97) wait_publish(sentH, 128, (u32)t, relH);
        if (bid < 96) {
            if (t > 0) wait_rel(relH, (u32)t);
            if (bid < 32) {
                const int b = bid;
                float* hsh = SH; float* red = SH + 1024; float* sc = SH + 1536;
                {
                    u32 u = ((const u32*)Hd)[(size_t)t*16384 + b*512 + tid];
                    hsh[2*tid]   = b2f_lo(u);
                    hsh[2*tid+1] = b2f_hi(u);
                }
                __syncthreads();
                {
                    int s = tid >> 3, p = tid & 7;
                    const uint4* ep = (const uint4*)(encPB + (size_t)(s*32+b)*1024 + p*128);
                    const float* hk = hsh + p*128;
                    float a0=0,a1=0,a2=0,a3=0;
#pragma unroll 4
                    for (int q8 = 0; q8 < 16; ++q8) {
                        uint4 u = ep[q8];
                        a0 += b2f_lo(u.x)*hk[q8*8+0] + b2f_hi(u.x)*hk[q8*8+1];
                        a1 += b2f_lo(u.y)*hk[q8*8+2] + b2f_hi(u.y)*hk[q8*8+3];
                        a2 += b2f_lo(u.z)*hk[q8*8+4] + b2f_hi(u.z)*hk[q8*8+5];
                        a3 += b2f_lo(u.w)*hk[q8*8+6] + b2f_hi(u.w)*hk[q8*8+7];
                    }
                    red[tid] = (a0+a1)+(a2+a3);
                }
                __syncthreads();
                if (tid < 64) {
                    float v = 0;
#pragma unroll
                    for (int pp = 0; pp < 8; ++pp) v += red[tid*8+pp];
                    float m = v;
                    for (int off = 32; off; off >>= 1) m = fmaxf(m, __shfl_xor(m, off));
                    float e = __expf(v - m);
                    float ss = e;
                    for (int off = 32; off; off >>= 1) ss += __shfl_xor(ss, off);
                    sc[tid] = e / ss;
                }
                __syncthreads();
                {
                    const u32* eo = (const u32*)EOAb + (size_t)b*32768 + tid;
                    float p0 = 0, p1 = 0;
#pragma unroll 8
                    for (int s = 0; s < 64; ++s) {
                        u32 u = eo[(size_t)s*512];
                        float w = sc[s];
                        p0 += w*b2f_lo(u); p1 += w*b2f_hi(u);
                    }
                    u32 pk = (u32)f2b(p0) | ((u32)f2b(p1) << 16);
                    st_wt_u32((u32*)PEOb + (size_t)t*16384 + b*512 + tid, pk);
                }
            } else {
                const u16* Ah = Hd + (size_t)t*32768 + (size_t)(mth*16+lr)*1024 + kqh*256 + lk8;
                short8 av[8];
#pragma unroll
                for (int i = 0; i < 8; ++i) av[i] = *(const short8*)(Ah + i*32);
                f32x4 acc = {0.f,0.f,0.f,0.f};
#pragma unroll
                for (int i = 0; i < 8; ++i)
                    acc = __builtin_amdgcn_mfma_f32_16x16x32_bf16(av[i], wh[i], acc, 0, 0, 0);
#pragma unroll
                for (int r = 0; r < 4; ++r) SH[wv*256 + lane*4 + r] = acc[r];
                __syncthreads();
                if (wv < 2) {
#pragma unroll
                    for (int r = 0; r < 4; ++r) {
                        float sum = SH[(wv+0)*256 + lane*4 + r] + SH[(wv+2)*256 + lane*4 + r]
                                  + SH[(wv+4)*256 + lane*4 + r] + SH[(wv+6)*256 + lane*4 + r];
                        int m = wv*16 + (lane>>4)*4 + r;
                        st_wt_u16(hAb + (size_t)t*32768 + (size_t)m*1024 + nth*16 + (lane&15),
                                  f2b(sum));
                    }
                }
            }
            __syncthreads();
            if (tid == 0) st_wt_u32(sentA + (size_t)bid*32, (u32)(t+1));
        }

        // ======== Phase B ========
        if (bid == 96) wait_publish(sentA, 96, (u32)(t+1), relA);
        else           wait_rel(relA, (u32)(t+1));
        {
            const u32* pe = (const u32*)PEOb + (size_t)t*16384;
            const u32* ha = (const u32*)hAb + (size_t)t*16384;
#pragma unroll
            for (int ii = 0; ii < 32; ++ii) {
                int idx = tid + ii*512;
                u32 up = pe[idx], uh = ha[idx];
                float c0 = ftanh(b2f_lo(up) + b2f_lo(uh));
                float c1 = ftanh(b2f_hi(up) + b2f_hi(uh));
                int b = idx >> 9, nu = idx & 511;
                CT[b*516 + nu] = (u32)f2b(c0) | ((u32)f2b(c1) << 16);
            }
            __syncthreads();

            f32x4 a0 = {0.f,0.f,0.f,0.f}, a1 = {0.f,0.f,0.f,0.f};
            if (kqB < 2) {
                const u32* c0p = CT + (lr)*516 + kqB*256 + (lk8 >> 1);
                const u32* c1p = CT + (16+lr)*516 + kqB*256 + (lk8 >> 1);
#pragma unroll
                for (int i = 0; i < 16; ++i) {
                    short8 v0 = *(const short8*)(c0p + i*16);
                    short8 v1 = *(const short8*)(c1p + i*16);
                    a0 = __builtin_amdgcn_mfma_f32_16x16x32_bf16(v0, wp[i], a0, 0, 0, 0);
                    a1 = __builtin_amdgcn_mfma_f32_16x16x32_bf16(v1, wp[i], a1, 0, 0, 0);
                }
            } else {
                const u16* h0p = Hd + (size_t)t*32768 + (size_t)(lr)*1024 + (kqB-2)*512 + lk8;
                const u16* h1p = Hd + (size_t)t*32768 + (size_t)(16+lr)*1024 + (kqB-2)*512 + lk8;
#pragma unroll
                for (int i = 0; i < 16; ++i) {
                    short8 v0 = *(const short8*)(h0p + i*32);
                    short8 v1 = *(const short8*)(h1p + i*32);
                    a0 = __builtin_amdgcn_mfma_f32_16x16x32_bf16(v0, wp[i], a0, 0, 0, 0);
                    a1 = __builtin_amdgcn_mfma_f32_16x16x32_bf16(v1, wp[i], a1, 0, 0, 0);
                }
            }
#pragma unroll
            for (int r = 0; r < 4; ++r) {
                SH[wv*512 + lane*4 + r] = a0[r];
                SH[wv*512 + 256 + lane*4 + r] = a1[r];
            }
            __syncthreads();
            if (wv < 2) {
                const int nt = wv;
                float* T0 = SH + 4096 + (wv*2+0)*272;
                float* T1 = SH + 4096 + (wv*2+1)*272;
#pragma unroll
                for (int r = 0; r < 4; ++r) {
                    float s0 = SH[(nt+0)*512 + lane*4 + r] + SH[(nt+2)*512 + lane*4 + r]
                             + SH[(nt+4)*512 + lane*4 + r] + SH[(nt+6)*512 + lane*4 + r];
                    float s1 = SH[(nt+0)*512 + 256 + lane*4 + r] + SH[(nt+2)*512 + 256 + lane*4 + r]
                             + SH[(nt+4)*512 + 256 + lane*4 + r] + SH[(nt+6)*512 + 256 + lane*4 + r];
                    int rr = ((lane>>4)*4 + r)*17 + (lane&15);
                    T0[rr] = s0;
                    T1[rr] = s1;
                }
                __builtin_amdgcn_sched_barrier(0);
                {
                    ushort4 xr = *(const ushort4*)(Xe + (size_t)(t*32 + b_l)*4096 + jdB*4);
                    float gi = T0[b_l*17 + jjq*4 + 0] + us2f(xr.x);
                    float gf = T0[b_l*17 + jjq*4 + 1] + us2f(xr.y);
                    float gg = T0[b_l*17 + jjq*4 + 2] + us2f(xr.z);
                    float go = T0[b_l*17 + jjq*4 + 3] + us2f(xr.w);
                    float c2 = sigf(gf)*cdec0 + sigf(gi)*ftanh(gg);
                    float h2 = sigf(go)*ftanh(c2);
                    cdec0 = c2;
                    st_wt_u16(Hd + (size_t)(t+1)*32768 + (size_t)b_l*1024 + jdB, f2b(h2));
                }
                {
                    ushort4 xr = *(const ushort4*)(Xe + (size_t)(t*32 + 16 + b_l)*4096 + jdB*4);
                    float gi = T1[b_l*17 + jjq*4 + 0] + us2f(xr.x);
                    float gf = T1[b_l*17 + jjq*4 + 1] + us2f(xr.y);
                    float gg = T1[b_l*17 + jjq*4 + 2] + us2f(xr.z);
                    float go = T1[b_l*17 + jjq*4 + 3] + us2f(xr.w);
                    float c2 = sigf(gf)*cdec1 + sigf(gi)*ftanh(gg);
                    float h2 = sigf(go)*ftanh(c2);
                    cdec1 = c2;
                    st_wt_u16(Hd + (size_t)(t+1)*32768 + (size_t)(16+b_l)*1024 + jdB, f2b(h2));
                }
            }
            __syncthreads();
            if (tid == 0) st_wt_u32(sentH + (size_t)bid*32, (u32)(t+1));
        }
    }
    if (bid == 97) wait_publish(sentH, 128, 63u, relH);
}

// ---------------- log-softmax ----------------
__global__ __launch_bounds__(256) void k_lsm(float* __restrict__ out) {
    long row = 32 + blockIdx.x;
    float* p = out + row*32000L;
    float4* p4 = (float4*)p;
    int tid = threadIdx.x;
    __shared__ float sm[4];
    __shared__ float ss[4];
    float m = -1e30f;
    for (int i = tid; i < 8000; i += 256) {
        float4 v = p4[i];
        m = fmaxf(m, fmaxf(fmaxf(v.x, v.y), fmaxf(v.z, v.w)));
    }
    for (int off = 32; off; off >>= 1) m = fmaxf(m, __shfl_xor(m, off));
    if ((tid & 63) == 0) sm[tid >> 6] = m;
    __syncthreads();
    m = fmaxf(fmaxf(sm[0], sm[1]), fmaxf(sm[2], sm[3]));
    float s = 0;
    for (int i = tid; i < 8000; i += 256) {
        float4 v = p4[i];
        s += __expf(v.x - m) + __expf(v.y - m) + __expf(v.z - m) + __expf(v.w - m);
    }
    for (int off = 32; off; off >>= 1) s += __shfl_xor(s, off);
    if ((tid & 63) == 0) ss[tid >> 6] = s;
    __syncthreads();
    s = ss[0] + ss[1] + ss[2] + ss[3];
    float lse = m + __logf(s);
    for (int i = tid; i < 8000; i += 256) {
        float4 v = p4[i];
        v.x -= lse; v.y -= lse; v.z -= lse; v.w -= lse;
        p4[i] = v;
    }
}

// ---------------- launch ----------------

extern "C" void kernel_launch(void* const* d_in, const int* in_sizes, int n_in,
                              void* d_out, int out_size, void* d_ws, size_t ws_size,
                              hipStream_t stream) {
    const float* eemb  = (const float*)d_in[0];
    const float* ewihf = (const float*)d_in[1];
    const float* ewhhf = (const float*)d_in[2];
    const float* ebf   = (const float*)d_in[3];
    const float* ewihb = (const float*)d_in[4];
    const float* ewhhb = (const float*)d_in[5];
    const float* ebb   = (const float*)d_in[6];
    const float* awi   = (const float*)d_in[7];
    const float* awo   = (const float*)d_in[8];
    const float* dwih  = (const float*)d_in[9];
    const float* dwhh  = (const float*)d_in[10];
    const float* db    = (const float*)d_in[11];
    const float* demb  = (const float*)d_in[12];
    const float* genw  = (const float*)d_in[13];
    const float* genb  = (const float*)d_in[14];
    const int* srci    = (const int*)d_in[15];
    const int* trgi    = (const int*)d_in[16];
    float* out = (float*)d_out;

    float* F = (float*)d_ws;
    u32* S       = (u32*)F;
    u32* sentE   = S;                      // 64 x 32
    u32* sentA   = S + 2048;               // 96 x 32
    u32* sentH   = S + 5120;               // 128 x 32
    u32* relE    = S + 13312;              // 4 x 32
    u32* relA    = S + 13440;              // 32
    u32* relH    = S + 13472;              // 32
    float* cfin  = F + 16384;              // 32768 floats
    u16*   U     = (u16*)(F + 49152);

    u16* Xf_    = U;                       // 2048x2048
    u16* Xb_    = U + 4194304u;            // 2048x2048
    u16* Xe_    = U + 8388608u;            // 2016x4096
    u16* WencB  = U + 16646144u;           // 2 x 2048x512
    u16* awiTB  = U + 18743296u;           // 1024x1024
    u16* awoB   = U + 19791872u;           // 1024x2048
    u16* WdecB  = U + 21889024u;           // 4096x2048
    u16* genw_b = U + 30277632u;           // 32000x1024
    u16* encBX  = U + 63045632u;           // 65 x 32x1024
    u16* Hd     = U + 65175552u;           // 65 x 32x1024
    u16* PEOb   = U + 67305472u;           // 63 x 32x1024
    u16* hAb    = U + 69369856u;           // 63 x 32x1024
    u16* encPB  = U + 71434240u;           // 2048x1024
    u16* EOAb   = U + 73531392u;           // 32 x 64 x 1024

    k_zero<<<1024, 256, 0, stream>>>(out, 1024000L);   // t=0 output rows

    k_xw<<<dim3(32, 64), 256, 0, stream>>>(eemb, srci, ewihf, 300, 0, ebf, Xf_, 2048, 511, 9);
    k_xw<<<dim3(32, 64), 256, 0, stream>>>(eemb, srci, ewihb, 300, 0, ebb, Xb_, 2048, 511, 9);
    k_xw<<<dim3(64, 63), 256, 0, stream>>>(demb, trgi, dwih, 1324, 1024, db, Xe_, 4096, 1023, 10);

    k_wenc2<<<8192, 256, 0, stream>>>(ewhhf, ewhhb, WencB, F, (float*)encBX);

    k_enc<<<256, 512, 0, stream>>>(Xf_, Xb_, WencB, encBX, cfin, sentE, relE,
                                   awi, awo, dwih, dwhh, genw,
                                   awiTB, awoB, WdecB, genw_b);
    k_mid<<<1024, 256, 0, stream>>>(encBX, awiTB, awoB, encPB, EOAb, Hd);

    k_dec<<<256, 512, 0, stream>>>(Xe_, awoB, WdecB, encPB, EOAb,
                                   Hd, PEOb, hAb, cfin,
                                   genw_b, genb, out,
                                   sentA, sentH, relA, relH);

    k_lsm<<<2016, 256, 0, stream>>>(out);
}